// Round 1
// baseline (602.338 us; speedup 1.0000x reference)
//
#include <hip/hip_runtime.h>
#include <stdint.h>

typedef __bf16 bf16x8 __attribute__((ext_vector_type(8)));
typedef float f32x4 __attribute__((ext_vector_type(4)));
typedef unsigned short u16x8 __attribute__((ext_vector_type(8)));

__device__ __forceinline__ unsigned short f2bf(float f) {
  union { float f; uint32_t u; } v; v.f = f;
  uint32_t r = v.u + 0x7FFFu + ((v.u >> 16) & 1u);  // RNE
  return (unsigned short)(r >> 16);
}

__device__ __forceinline__ f32x4 mfma16(bf16x8 a, bf16x8 b, f32x4 c) {
  return __builtin_amdgcn_mfma_f32_16x16x32_bf16(a, b, c, 0, 0, 0);
}

__device__ __forceinline__ void gload_lds16(const unsigned short* g, unsigned short* l) {
  __builtin_amdgcn_global_load_lds(
      (const __attribute__((address_space(1))) void*)g,
      (__attribute__((address_space(3))) void*)l, 16, 0, 0);
}

// ---------------- x fp32 -> bf16 ----------------
__global__ __launch_bounds__(256) void convert_f32_bf16(const float* __restrict__ in,
                                                        unsigned short* __restrict__ outp) {
  int i = blockIdx.x * 256 + threadIdx.x;
  const float4* p = (const float4*)in + (size_t)i * 2;
  float4 a = p[0], b = p[1];
  u16x8 o;
  o[0] = f2bf(a.x); o[1] = f2bf(a.y); o[2] = f2bf(a.z); o[3] = f2bf(a.w);
  o[4] = f2bf(b.x); o[5] = f2bf(b.y); o[6] = f2bf(b.z); o[7] = f2bf(b.w);
  *(u16x8*)&outp[(size_t)i * 8] = o;
}

// ---------------- w [K][N] fp32 -> wT [N][K] bf16 ----------------
__global__ __launch_bounds__(256) void transpose_to_bf16(const float* __restrict__ w,
                                                         unsigned short* __restrict__ wT,
                                                         int K, int N) {
  __shared__ unsigned short tile[64][72];
  const int n0 = blockIdx.x * 64, k0 = blockIdx.y * 64;
  const int t = threadIdx.x;
  {
    const int r = t >> 4, c0 = (t & 15) * 4;
#pragma unroll
    for (int i = 0; i < 4; ++i) {
      int rr = r + i * 16;
      float4 v = *(const float4*)&w[(size_t)(k0 + rr) * N + n0 + c0];
      tile[c0 + 0][rr] = f2bf(v.x);
      tile[c0 + 1][rr] = f2bf(v.y);
      tile[c0 + 2][rr] = f2bf(v.z);
      tile[c0 + 3][rr] = f2bf(v.w);
    }
  }
  __syncthreads();
  {
    const int c = t >> 2, r0 = (t & 3) * 16;
    u16x8 o1, o2;
#pragma unroll
    for (int i = 0; i < 8; ++i) { o1[i] = tile[c][r0 + i]; o2[i] = tile[c][r0 + 8 + i]; }
    *(u16x8*)&wT[(size_t)(n0 + c) * K + k0 + r0] = o1;
    *(u16x8*)&wT[(size_t)(n0 + c) * K + k0 + r0 + 8] = o2;
  }
}

// ---------------- QKV GEMM: [8192,1024] x [1024,3072] + bias ----------------
// A = xbf [8192][1024] bf16 row-major (k contiguous)
// B = wT  [3072][1024] bf16 (n-major, k contiguous)
// out: q,k -> [B=4][H=16][S=2048][64] bf16 ; v -> [4][16][64][2048] bf16 (transposed)
__global__ __launch_bounds__(256) void qkv_gemm(const unsigned short* __restrict__ xbf,
                                                const unsigned short* __restrict__ wT,
                                                const float* __restrict__ bias,
                                                unsigned short* __restrict__ qb,
                                                unsigned short* __restrict__ kb,
                                                unsigned short* __restrict__ vtb) {
  __shared__ unsigned short As[128 * 32];
  __shared__ unsigned short Bs[128 * 32];
  const int tid = threadIdx.x, lane = tid & 63, wave = tid >> 6;
  const int mb = blockIdx.y * 128, nb = blockIdx.x * 128;
  const int wr = (wave >> 1) * 64, wc = (wave & 1) * 64;
  const int fr = lane & 15, fk = (lane >> 4) * 8;
  f32x4 acc[4][4] = {};
  for (int kt = 0; kt < 1024; kt += 32) {
    __syncthreads();
#pragma unroll
    for (int i = 0; i < 2; ++i) {
      int ch = wave * 128 + i * 64 + lane;
      int r = ch >> 2, ko = (ch & 3) * 8;
      gload_lds16(xbf + (size_t)(mb + r) * 1024 + kt + ko, &As[(wave * 128 + i * 64) * 8]);
      gload_lds16(wT + (size_t)(nb + r) * 1024 + kt + ko, &Bs[(wave * 128 + i * 64) * 8]);
    }
    __syncthreads();
    bf16x8 a[4], bq[4];
#pragma unroll
    for (int m = 0; m < 4; ++m) a[m] = *(const bf16x8*)&As[(wr + m * 16 + fr) * 32 + fk];
#pragma unroll
    for (int n = 0; n < 4; ++n) bq[n] = *(const bf16x8*)&Bs[(wc + n * 16 + fr) * 32 + fk];
#pragma unroll
    for (int m = 0; m < 4; ++m)
#pragma unroll
      for (int n = 0; n < 4; ++n) acc[m][n] = mfma16(a[m], bq[n], acc[m][n]);
  }
#pragma unroll
  for (int m = 0; m < 4; ++m)
#pragma unroll
    for (int n = 0; n < 4; ++n) {
      int col = nb + wc + n * 16 + fr;
      float bv = bias[col];
      int type = col >> 10, cc = col & 1023, h = cc >> 6, d = cc & 63;
#pragma unroll
      for (int j = 0; j < 4; ++j) {
        int row = mb + wr + m * 16 + (lane >> 4) * 4 + j;
        int bidx = row >> 11, s = row & 2047;
        unsigned short ov = f2bf(acc[m][n][j] + bv);
        if (type == 0)
          qb[(((size_t)(bidx * 16 + h)) * 2048 + s) * 64 + d] = ov;
        else if (type == 1)
          kb[(((size_t)(bidx * 16 + h)) * 2048 + s) * 64 + d] = ov;
        else
          vtb[(((size_t)(bidx * 16 + h)) * 64 + d) * 2048 + s] = ov;
      }
    }
}

// ---------------- flash attention ----------------
// grid: (32 q-tiles, 64 bh). block = 256 = 4 waves; each wave: 16 q-rows.
__global__ __launch_bounds__(256) void attn_kernel(const unsigned short* __restrict__ qg,
                                                   const unsigned short* __restrict__ kgl,
                                                   const unsigned short* __restrict__ vtg,
                                                   unsigned short* __restrict__ attnb) {
  __shared__ unsigned short Pl[4][16][64];
  const int tid = threadIdx.x;
  const int lane = tid & 63, wave = tid >> 6;
  const int fr = lane & 15, kgp = lane >> 4, fk = kgp * 8;
  const int bh = blockIdx.y;
  const int b = bh >> 4, h = bh & 15;
  const unsigned short* Q = qg + (size_t)bh * 2048 * 64;
  const unsigned short* K = kgl + (size_t)bh * 2048 * 64;
  const unsigned short* V = vtg + (size_t)bh * 64 * 2048;
  const int q0 = blockIdx.x * 64 + wave * 16;

  bf16x8 aq[2];
#pragma unroll
  for (int c = 0; c < 2; ++c) aq[c] = *(const bf16x8*)&Q[(size_t)(q0 + fr) * 64 + c * 32 + fk];

  float mrun[4], lrun[4];
  f32x4 o[4];
#pragma unroll
  for (int r = 0; r < 4; ++r) { mrun[r] = -1e30f; lrun[r] = 0.f; }
#pragma unroll
  for (int c = 0; c < 4; ++c) o[c] = (f32x4){0.f, 0.f, 0.f, 0.f};

  for (int kb = 0; kb < 2048; kb += 64) {
    f32x4 s4[4];
#pragma unroll
    for (int t = 0; t < 4; ++t) {
      bf16x8 bk0 = *(const bf16x8*)&K[(size_t)(kb + t * 16 + fr) * 64 + fk];
      bf16x8 bk1 = *(const bf16x8*)&K[(size_t)(kb + t * 16 + fr) * 64 + 32 + fk];
      f32x4 ss = (f32x4){0.f, 0.f, 0.f, 0.f};
      ss = mfma16(aq[0], bk0, ss);
      ss = mfma16(aq[1], bk1, ss);
      s4[t] = ss * 0.125f;  // hd^-0.5
    }
    float fs[4];
#pragma unroll
    for (int r = 0; r < 4; ++r) {
      float mx = fmaxf(fmaxf(s4[0][r], s4[1][r]), fmaxf(s4[2][r], s4[3][r]));
      mx = fmaxf(mx, __shfl_xor(mx, 1));
      mx = fmaxf(mx, __shfl_xor(mx, 2));
      mx = fmaxf(mx, __shfl_xor(mx, 4));
      mx = fmaxf(mx, __shfl_xor(mx, 8));
      float nm = fmaxf(mrun[r], mx);
      fs[r] = __expf(mrun[r] - nm);
      mrun[r] = nm;
    }
#pragma unroll
    for (int t = 0; t < 4; ++t)
#pragma unroll
      for (int r = 0; r < 4; ++r) s4[t][r] = __expf(s4[t][r] - mrun[r]);
#pragma unroll
    for (int r = 0; r < 4; ++r) {
      float rs = s4[0][r] + s4[1][r] + s4[2][r] + s4[3][r];
      rs += __shfl_xor(rs, 1);
      rs += __shfl_xor(rs, 2);
      rs += __shfl_xor(rs, 4);
      rs += __shfl_xor(rs, 8);
      lrun[r] = lrun[r] * fs[r] + rs;
    }
#pragma unroll
    for (int c = 0; c < 4; ++c)
#pragma unroll
      for (int r = 0; r < 4; ++r) o[c][r] *= fs[r];
    __syncthreads();
#pragma unroll
    for (int t = 0; t < 4; ++t)
#pragma unroll
      for (int r = 0; r < 4; ++r) Pl[wave][kgp * 4 + r][t * 16 + fr] = f2bf(s4[t][r]);
    __syncthreads();
    bf16x8 pa[2];
#pragma unroll
    for (int c = 0; c < 2; ++c) pa[c] = *(const bf16x8*)&Pl[wave][fr][c * 32 + fk];
#pragma unroll
    for (int c = 0; c < 4; ++c)
#pragma unroll
      for (int kc = 0; kc < 2; ++kc) {
        bf16x8 bv = *(const bf16x8*)&V[(size_t)(c * 16 + fr) * 2048 + kb + kc * 32 + fk];
        o[c] = mfma16(pa[kc], bv, o[c]);
      }
  }
  float inv[4];
#pragma unroll
  for (int r = 0; r < 4; ++r) inv[r] = 1.0f / lrun[r];
#pragma unroll
  for (int c = 0; c < 4; ++c)
#pragma unroll
    for (int r = 0; r < 4; ++r) {
      int s = q0 + kgp * 4 + r;
      attnb[((size_t)(b * 2048 + s)) * 1024 + h * 64 + c * 16 + fr] = f2bf(o[c][r] * inv[r]);
    }
}

// ---------------- proj GEMM: attn[8192,1024] x [1024,1024] + bias -> fp32 out ----------------
__global__ __launch_bounds__(256) void proj_gemm(const unsigned short* __restrict__ abf,
                                                 const unsigned short* __restrict__ wT,
                                                 const float* __restrict__ bias,
                                                 float* __restrict__ outp) {
  __shared__ unsigned short As[128 * 32];
  __shared__ unsigned short Bs[128 * 32];
  const int tid = threadIdx.x, lane = tid & 63, wave = tid >> 6;
  const int mb = blockIdx.y * 128, nb = blockIdx.x * 128;
  const int wr = (wave >> 1) * 64, wc = (wave & 1) * 64;
  const int fr = lane & 15, fk = (lane >> 4) * 8;
  f32x4 acc[4][4] = {};
  for (int kt = 0; kt < 1024; kt += 32) {
    __syncthreads();
#pragma unroll
    for (int i = 0; i < 2; ++i) {
      int ch = wave * 128 + i * 64 + lane;
      int r = ch >> 2, ko = (ch & 3) * 8;
      gload_lds16(abf + (size_t)(mb + r) * 1024 + kt + ko, &As[(wave * 128 + i * 64) * 8]);
      gload_lds16(wT + (size_t)(nb + r) * 1024 + kt + ko, &Bs[(wave * 128 + i * 64) * 8]);
    }
    __syncthreads();
    bf16x8 a[4], bq[4];
#pragma unroll
    for (int m = 0; m < 4; ++m) a[m] = *(const bf16x8*)&As[(wr + m * 16 + fr) * 32 + fk];
#pragma unroll
    for (int n = 0; n < 4; ++n) bq[n] = *(const bf16x8*)&Bs[(wc + n * 16 + fr) * 32 + fk];
#pragma unroll
    for (int m = 0; m < 4; ++m)
#pragma unroll
      for (int n = 0; n < 4; ++n) acc[m][n] = mfma16(a[m], bq[n], acc[m][n]);
  }
#pragma unroll
  for (int m = 0; m < 4; ++m)
#pragma unroll
    for (int n = 0; n < 4; ++n) {
      int col = nb + wc + n * 16 + fr;
      float bv = bias[col];
#pragma unroll
      for (int j = 0; j < 4; ++j) {
        int row = mb + wr + m * 16 + (lane >> 4) * 4 + j;
        outp[(size_t)row * 1024 + col] = acc[m][n][j] + bv;
      }
    }
}

extern "C" void kernel_launch(void* const* d_in, const int* in_sizes, int n_in,
                              void* d_out, int out_size, void* d_ws, size_t ws_size,
                              hipStream_t stream) {
  const float* x = (const float*)d_in[0];
  const float* w_qkv = (const float*)d_in[1];
  const float* b_qkv = (const float*)d_in[2];
  const float* w_proj = (const float*)d_in[3];
  const float* b_proj = (const float*)d_in[4];
  float* outp = (float*)d_out;
  char* ws = (char*)d_ws;

  // workspace layout (bytes)
  const size_t OFF_XBF = 0;                 // 16,777,216 (also reused as attn output)
  const size_t OFF_WTQKV = 16777216;        //  6,291,456
  const size_t OFF_WTPROJ = 23068672;       //  2,097,152
  const size_t OFF_Q = 25165824;            // 16,777,216
  const size_t OFF_K = 41943040;            // 16,777,216
  const size_t OFF_VT = 58720256;           // 16,777,216
  const size_t NEED = 75497472;
  if (ws_size < NEED) return;

  unsigned short* xbf = (unsigned short*)(ws + OFF_XBF);
  unsigned short* wTqkv = (unsigned short*)(ws + OFF_WTQKV);
  unsigned short* wTproj = (unsigned short*)(ws + OFF_WTPROJ);
  unsigned short* qbuf = (unsigned short*)(ws + OFF_Q);
  unsigned short* kbuf = (unsigned short*)(ws + OFF_K);
  unsigned short* vtbuf = (unsigned short*)(ws + OFF_VT);
  unsigned short* attnb = xbf;  // alias: xbf dead after qkv_gemm

  hipLaunchKernelGGL(convert_f32_bf16, dim3(4096), dim3(256), 0, stream, x, xbf);
  hipLaunchKernelGGL(transpose_to_bf16, dim3(48, 16), dim3(256), 0, stream, w_qkv, wTqkv, 1024, 3072);
  hipLaunchKernelGGL(transpose_to_bf16, dim3(16, 16), dim3(256), 0, stream, w_proj, wTproj, 1024, 1024);
  hipLaunchKernelGGL(qkv_gemm, dim3(24, 64), dim3(256), 0, stream, xbf, wTqkv, b_qkv, qbuf, kbuf, vtbuf);
  hipLaunchKernelGGL(attn_kernel, dim3(32, 64), dim3(256), 0, stream, qbuf, kbuf, vtbuf, attnb);
  hipLaunchKernelGGL(proj_gemm, dim3(8, 64), dim3(256), 0, stream, attnb, wTproj, b_proj, outp);
}

// Round 2
// 266.651 us; speedup vs baseline: 2.2589x; 2.2589x over previous
//
#include <hip/hip_runtime.h>
#include <stdint.h>

typedef __bf16 bf16x8 __attribute__((ext_vector_type(8)));
typedef float f32x4 __attribute__((ext_vector_type(4)));
typedef unsigned short u16x8 __attribute__((ext_vector_type(8)));
typedef unsigned short u16x4 __attribute__((ext_vector_type(4)));

__device__ __forceinline__ unsigned short f2bf(float f) {
  union { float f; uint32_t u; } v; v.f = f;
  uint32_t r = v.u + 0x7FFFu + ((v.u >> 16) & 1u);  // RNE
  return (unsigned short)(r >> 16);
}

__device__ __forceinline__ f32x4 mfma16(bf16x8 a, bf16x8 b, f32x4 c) {
  return __builtin_amdgcn_mfma_f32_16x16x32_bf16(a, b, c, 0, 0, 0);
}

__device__ __forceinline__ void gload_lds16(const unsigned short* g, unsigned short* l) {
  __builtin_amdgcn_global_load_lds(
      (const __attribute__((address_space(1))) void*)g,
      (__attribute__((address_space(3))) void*)l, 16, 0, 0);
}

// 0.125 (hd^-0.5) * log2(e): folded into Q so softmax runs in exp2 domain.
#define SCALEQ 0.18033688011112042f

// ---------------- x fp32 -> bf16 ----------------
__global__ __launch_bounds__(256) void convert_f32_bf16(const float* __restrict__ in,
                                                        unsigned short* __restrict__ outp) {
  int i = blockIdx.x * 256 + threadIdx.x;
  const float4* p = (const float4*)in + (size_t)i * 2;
  float4 a = p[0], b = p[1];
  u16x8 o;
  o[0] = f2bf(a.x); o[1] = f2bf(a.y); o[2] = f2bf(a.z); o[3] = f2bf(a.w);
  o[4] = f2bf(b.x); o[5] = f2bf(b.y); o[6] = f2bf(b.z); o[7] = f2bf(b.w);
  *(u16x8*)&outp[(size_t)i * 8] = o;
}

// ---------------- w [K][N] fp32 -> wT [N][K] bf16 ----------------
__global__ __launch_bounds__(256) void transpose_to_bf16(const float* __restrict__ w,
                                                         unsigned short* __restrict__ wT,
                                                         int K, int N) {
  __shared__ unsigned short tile[64][72];
  const int n0 = blockIdx.x * 64, k0 = blockIdx.y * 64;
  const int t = threadIdx.x;
  {
    const int r = t >> 4, c0 = (t & 15) * 4;
#pragma unroll
    for (int i = 0; i < 4; ++i) {
      int rr = r + i * 16;
      float4 v = *(const float4*)&w[(size_t)(k0 + rr) * N + n0 + c0];
      tile[c0 + 0][rr] = f2bf(v.x);
      tile[c0 + 1][rr] = f2bf(v.y);
      tile[c0 + 2][rr] = f2bf(v.z);
      tile[c0 + 3][rr] = f2bf(v.w);
    }
  }
  __syncthreads();
  {
    const int c = t >> 2, r0 = (t & 3) * 16;
    u16x8 o1, o2;
#pragma unroll
    for (int i = 0; i < 8; ++i) { o1[i] = tile[c][r0 + i]; o2[i] = tile[c][r0 + 8 + i]; }
    *(u16x8*)&wT[(size_t)(n0 + c) * K + k0 + r0] = o1;
    *(u16x8*)&wT[(size_t)(n0 + c) * K + k0 + r0 + 8] = o2;
  }
}

// ---------------- QKV GEMM: [8192,1024] x [1024,3072] + bias ----------------
__global__ __launch_bounds__(256) void qkv_gemm(const unsigned short* __restrict__ xbf,
                                                const unsigned short* __restrict__ wT,
                                                const float* __restrict__ bias,
                                                unsigned short* __restrict__ qb,
                                                unsigned short* __restrict__ kb,
                                                unsigned short* __restrict__ vtb) {
  __shared__ unsigned short As[128 * 32];
  __shared__ unsigned short Bs[128 * 32];
  const int tid = threadIdx.x, lane = tid & 63, wave = tid >> 6;
  const int mb = blockIdx.y * 128, nb = blockIdx.x * 128;
  const int wr = (wave >> 1) * 64, wc = (wave & 1) * 64;
  const int fr = lane & 15, fk = (lane >> 4) * 8;
  f32x4 acc[4][4] = {};
  for (int kt = 0; kt < 1024; kt += 32) {
    __syncthreads();
#pragma unroll
    for (int i = 0; i < 2; ++i) {
      int ch = wave * 128 + i * 64 + lane;
      int r = ch >> 2, ko = (ch & 3) * 8;
      gload_lds16(xbf + (size_t)(mb + r) * 1024 + kt + ko, &As[(wave * 128 + i * 64) * 8]);
      gload_lds16(wT + (size_t)(nb + r) * 1024 + kt + ko, &Bs[(wave * 128 + i * 64) * 8]);
    }
    __syncthreads();
    bf16x8 a[4], bq[4];
#pragma unroll
    for (int m = 0; m < 4; ++m) a[m] = *(const bf16x8*)&As[(wr + m * 16 + fr) * 32 + fk];
#pragma unroll
    for (int n = 0; n < 4; ++n) bq[n] = *(const bf16x8*)&Bs[(wc + n * 16 + fr) * 32 + fk];
#pragma unroll
    for (int m = 0; m < 4; ++m)
#pragma unroll
      for (int n = 0; n < 4; ++n) acc[m][n] = mfma16(a[m], bq[n], acc[m][n]);
  }
#pragma unroll
  for (int m = 0; m < 4; ++m)
#pragma unroll
    for (int n = 0; n < 4; ++n) {
      int col = nb + wc + n * 16 + fr;
      float bv = bias[col];
      int type = col >> 10, cc = col & 1023, h = cc >> 6, d = cc & 63;
#pragma unroll
      for (int j = 0; j < 4; ++j) {
        int row = mb + wr + m * 16 + (lane >> 4) * 4 + j;
        int bidx = row >> 11, s = row & 2047;
        float val = acc[m][n][j] + bv;
        if (type == 0)
          qb[(((size_t)(bidx * 16 + h)) * 2048 + s) * 64 + d] = f2bf(val * SCALEQ);
        else if (type == 1)
          kb[(((size_t)(bidx * 16 + h)) * 2048 + s) * 64 + d] = f2bf(val);
        else
          vtb[(((size_t)(bidx * 16 + h)) * 64 + d) * 2048 + s] = f2bf(val);
      }
    }
}

// ---------------- flash attention (swapped-QK^T, per-wave independent) ----------------
// grid: (8 q-tiles, 64 bh) remapped for XCD locality. block = 256 = 4 waves.
// Each wave: 64 q-rows, iterates 2048 keys in 64-key tiles.
__global__ __launch_bounds__(256, 2) void attn_kernel(const unsigned short* __restrict__ qg,
                                                      const unsigned short* __restrict__ kgl,
                                                      const unsigned short* __restrict__ vtg,
                                                      unsigned short* __restrict__ attnb) {
  __shared__ char Pl[4][8192];  // per-wave P buffer: [mq 4][q 16][k 64] bf16, XOR-swizzled rows
  const int tid = threadIdx.x;
  const int lane = tid & 63, wave = tid >> 6;
  const int fr = lane & 15, kgp = lane >> 4;
  const int fk = kgp * 8;

  // XCD-locality remap: the 8 q-tiles of one bh land on one XCD (L2 = 4MB = K+V+Q of 8 bh)
  const int L = blockIdx.y * 8 + blockIdx.x;
  const int xcd = L & 7, sl = L >> 3;
  const int bh = xcd * 8 + (sl & 7);
  const int qt = sl >> 3;

  const int b = bh >> 4, h = bh & 15;
  const unsigned short* Qg = qg + (size_t)bh * 2048 * 64;
  const unsigned short* Kg = kgl + (size_t)bh * 2048 * 64;
  const unsigned short* Vg = vtg + (size_t)bh * 64 * 2048;
  const int q0w = qt * 256 + wave * 64;

  // Q fragments (pre-scaled by 0.125*log2e in qkv epilogue), persistent
  bf16x8 qf[4][2];
#pragma unroll
  for (int mq = 0; mq < 4; ++mq)
#pragma unroll
    for (int c = 0; c < 2; ++c)
      qf[mq][c] = *(const bf16x8*)&Qg[(size_t)(q0w + mq * 16 + fr) * 64 + c * 32 + fk];

  float mrun[4], lrun[4];
  f32x4 o[4][4];  // [mq][dc]
#pragma unroll
  for (int mq = 0; mq < 4; ++mq) {
    mrun[mq] = -1e30f; lrun[mq] = 0.f;
#pragma unroll
    for (int dc = 0; dc < 4; ++dc) o[mq][dc] = (f32x4){0.f, 0.f, 0.f, 0.f};
  }

  const int swz = (fr & 7) << 4;  // byte-XOR swizzle for P rows
  char* Pw = &Pl[wave][0];

  for (int kb = 0; kb < 2048; kb += 64) {
    // ---- QK^T (swapped): s[mq][t] = S^T tile, lane holds k=16t+4kgp+j for q=mq*16+fr
    f32x4 s[4][4];
#pragma unroll
    for (int mq = 0; mq < 4; ++mq)
#pragma unroll
      for (int t = 0; t < 4; ++t) s[mq][t] = (f32x4){0.f, 0.f, 0.f, 0.f};
#pragma unroll
    for (int t = 0; t < 4; ++t) {
      const unsigned short* kr = &Kg[(size_t)(kb + t * 16 + fr) * 64];
      bf16x8 k0 = *(const bf16x8*)&kr[fk];
      bf16x8 k1 = *(const bf16x8*)&kr[32 + fk];
#pragma unroll
      for (int mq = 0; mq < 4; ++mq) {
        s[mq][t] = mfma16(k0, qf[mq][0], s[mq][t]);
        s[mq][t] = mfma16(k1, qf[mq][1], s[mq][t]);
      }
    }
    // ---- V fragments for this key tile (issued early to hide L2 latency)
    bf16x8 vf[4][2];
#pragma unroll
    for (int dc = 0; dc < 4; ++dc)
#pragma unroll
      for (int kc = 0; kc < 2; ++kc)
        vf[dc][kc] = *(const bf16x8*)&Vg[(size_t)(dc * 16 + fr) * 2048 + kb + kc * 32 + fk];

    // ---- online softmax per mq (rows q = mq*16+fr; reduce: in-lane + xor16/xor32)
#pragma unroll
    for (int mq = 0; mq < 4; ++mq) {
      f32x4 m4a = s[mq][0], m4b = s[mq][2];
#pragma unroll
      for (int j = 0; j < 4; ++j) {
        m4a[j] = fmaxf(m4a[j], s[mq][1][j]);
        m4b[j] = fmaxf(m4b[j], s[mq][3][j]);
      }
      float mx = fmaxf(fmaxf(fmaxf(m4a[0], m4a[1]), fmaxf(m4a[2], m4a[3])),
                       fmaxf(fmaxf(m4b[0], m4b[1]), fmaxf(m4b[2], m4b[3])));
      mx = fmaxf(mx, __shfl_xor(mx, 16));
      mx = fmaxf(mx, __shfl_xor(mx, 32));
      // T13 defer-rescale: skip when tile max doesn't exceed running max by >6 (p<=64)
      if (!__all(mx <= mrun[mq] + 6.0f)) {
        float nm = fmaxf(mrun[mq], mx);
        float fs = __builtin_amdgcn_exp2f(mrun[mq] - nm);
        mrun[mq] = nm;
        lrun[mq] *= fs;
        // broadcast fs into PV accumulator layout (row = kgp*4+j)
        f32x4 f4;
#pragma unroll
        for (int j = 0; j < 4; ++j) f4[j] = __shfl(fs, kgp * 4 + j);
#pragma unroll
        for (int dc = 0; dc < 4; ++dc) o[mq][dc] *= f4;
      }
      // exp2 + row-sum
      f32x4 r4 = (f32x4){0.f, 0.f, 0.f, 0.f};
      float mm = mrun[mq];
#pragma unroll
      for (int t = 0; t < 4; ++t) {
#pragma unroll
        for (int j = 0; j < 4; ++j) s[mq][t][j] = __builtin_amdgcn_exp2f(s[mq][t][j] - mm);
        r4 += s[mq][t];
      }
      float rs = (r4[0] + r4[1]) + (r4[2] + r4[3]);
      rs += __shfl_xor(rs, 16);
      rs += __shfl_xor(rs, 32);
      lrun[mq] += rs;
      // pack P -> bf16, swizzled ds_write_b64 (row q=fr, k=16t+4kgp..+3)
#pragma unroll
      for (int t = 0; t < 4; ++t) {
        u16x4 pk;
#pragma unroll
        for (int j = 0; j < 4; ++j) pk[j] = f2bf(s[mq][t][j]);
        *(u16x4*)(Pw + mq * 2048 + fr * 128 + ((t * 32 + kgp * 8) ^ swz)) = pk;
      }
    }
    // ---- PV: o[mq][dc] += P[mq] x V  (A-frags from swizzled LDS, same-wave RAW)
#pragma unroll
    for (int mq = 0; mq < 4; ++mq) {
      bf16x8 pa0 = *(const bf16x8*)(Pw + mq * 2048 + fr * 128 + ((kgp * 16) ^ swz));
      bf16x8 pa1 = *(const bf16x8*)(Pw + mq * 2048 + fr * 128 + ((64 + kgp * 16) ^ swz));
#pragma unroll
      for (int dc = 0; dc < 4; ++dc) {
        o[mq][dc] = mfma16(pa0, vf[dc][0], o[mq][dc]);
        o[mq][dc] = mfma16(pa1, vf[dc][1], o[mq][dc]);
      }
    }
  }

  // ---- epilogue: normalize by 1/l (broadcast into PV layout) and store
#pragma unroll
  for (int mq = 0; mq < 4; ++mq) {
    f32x4 inv4;
#pragma unroll
    for (int j = 0; j < 4; ++j) {
      float lv = __shfl(lrun[mq], kgp * 4 + j);
      inv4[j] = __builtin_amdgcn_rcpf(lv);
    }
#pragma unroll
    for (int dc = 0; dc < 4; ++dc)
#pragma unroll
      for (int j = 0; j < 4; ++j) {
        int q = q0w + mq * 16 + kgp * 4 + j;
        attnb[((size_t)(b * 2048 + q)) * 1024 + h * 64 + dc * 16 + fr] =
            f2bf(o[mq][dc][j] * inv4[j]);
      }
  }
}

// ---------------- proj GEMM: attn[8192,1024] x [1024,1024] + bias -> fp32 out ----------------
__global__ __launch_bounds__(256) void proj_gemm(const unsigned short* __restrict__ abf,
                                                 const unsigned short* __restrict__ wT,
                                                 const float* __restrict__ bias,
                                                 float* __restrict__ outp) {
  __shared__ unsigned short As[128 * 32];
  __shared__ unsigned short Bs[128 * 32];
  const int tid = threadIdx.x, lane = tid & 63, wave = tid >> 6;
  const int mb = blockIdx.y * 128, nb = blockIdx.x * 128;
  const int wr = (wave >> 1) * 64, wc = (wave & 1) * 64;
  const int fr = lane & 15, fk = (lane >> 4) * 8;
  f32x4 acc[4][4] = {};
  for (int kt = 0; kt < 1024; kt += 32) {
    __syncthreads();
#pragma unroll
    for (int i = 0; i < 2; ++i) {
      int ch = wave * 128 + i * 64 + lane;
      int r = ch >> 2, ko = (ch & 3) * 8;
      gload_lds16(abf + (size_t)(mb + r) * 1024 + kt + ko, &As[(wave * 128 + i * 64) * 8]);
      gload_lds16(wT + (size_t)(nb + r) * 1024 + kt + ko, &Bs[(wave * 128 + i * 64) * 8]);
    }
    __syncthreads();
    bf16x8 a[4], bq[4];
#pragma unroll
    for (int m = 0; m < 4; ++m) a[m] = *(const bf16x8*)&As[(wr + m * 16 + fr) * 32 + fk];
#pragma unroll
    for (int n = 0; n < 4; ++n) bq[n] = *(const bf16x8*)&Bs[(wc + n * 16 + fr) * 32 + fk];
#pragma unroll
    for (int m = 0; m < 4; ++m)
#pragma unroll
      for (int n = 0; n < 4; ++n) acc[m][n] = mfma16(a[m], bq[n], acc[m][n]);
  }
#pragma unroll
  for (int m = 0; m < 4; ++m)
#pragma unroll
    for (int n = 0; n < 4; ++n) {
      int col = nb + wc + n * 16 + fr;
      float bv = bias[col];
#pragma unroll
      for (int j = 0; j < 4; ++j) {
        int row = mb + wr + m * 16 + (lane >> 4) * 4 + j;
        outp[(size_t)row * 1024 + col] = acc[m][n][j] + bv;
      }
    }
}

extern "C" void kernel_launch(void* const* d_in, const int* in_sizes, int n_in,
                              void* d_out, int out_size, void* d_ws, size_t ws_size,
                              hipStream_t stream) {
  const float* x = (const float*)d_in[0];
  const float* w_qkv = (const float*)d_in[1];
  const float* b_qkv = (const float*)d_in[2];
  const float* w_proj = (const float*)d_in[3];
  const float* b_proj = (const float*)d_in[4];
  float* outp = (float*)d_out;
  char* ws = (char*)d_ws;

  const size_t OFF_XBF = 0;                 // 16,777,216 (also reused as attn output)
  const size_t OFF_WTQKV = 16777216;        //  6,291,456
  const size_t OFF_WTPROJ = 23068672;       //  2,097,152
  const size_t OFF_Q = 25165824;            // 16,777,216
  const size_t OFF_K = 41943040;            // 16,777,216
  const size_t OFF_VT = 58720256;           // 16,777,216
  const size_t NEED = 75497472;
  if (ws_size < NEED) return;

  unsigned short* xbf = (unsigned short*)(ws + OFF_XBF);
  unsigned short* wTqkv = (unsigned short*)(ws + OFF_WTQKV);
  unsigned short* wTproj = (unsigned short*)(ws + OFF_WTPROJ);
  unsigned short* qbuf = (unsigned short*)(ws + OFF_Q);
  unsigned short* kbuf = (unsigned short*)(ws + OFF_K);
  unsigned short* vtbuf = (unsigned short*)(ws + OFF_VT);
  unsigned short* attnb = xbf;  // alias: xbf dead after qkv_gemm

  hipLaunchKernelGGL(convert_f32_bf16, dim3(4096), dim3(256), 0, stream, x, xbf);
  hipLaunchKernelGGL(transpose_to_bf16, dim3(48, 16), dim3(256), 0, stream, w_qkv, wTqkv, 1024, 3072);
  hipLaunchKernelGGL(transpose_to_bf16, dim3(16, 16), dim3(256), 0, stream, w_proj, wTproj, 1024, 1024);
  hipLaunchKernelGGL(qkv_gemm, dim3(24, 64), dim3(256), 0, stream, xbf, wTqkv, b_qkv, qbuf, kbuf, vtbuf);
  hipLaunchKernelGGL(attn_kernel, dim3(8, 64), dim3(256), 0, stream, qbuf, kbuf, vtbuf, attnb);
  hipLaunchKernelGGL(proj_gemm, dim3(8, 64), dim3(256), 0, stream, attnb, wTproj, b_proj, outp);
}